// Round 9
// baseline (216.694 us; speedup 1.0000x reference)
//
#include <hip/hip_runtime.h>
#include <hip/hip_bf16.h>

// TAttention: B=16, C=32, N=1024, T=128, R=10
// Fast path (ws >= ~142MB):
//  K1 k_reduce_cw : k[b,n,t] = sum_c alpha[c]*x[...]; ALSO writes x_bf16
//     pre-swizzled in LDS-image slab layout (256R + 8W + 128W)
//  K2 kw_partial2 : p_w[b][r][ch32][t] partials
//  K3 scores_softmax3: reduce partials + scores + softmax -> att bf16
//  K4 out_gemm6   : reads x_bf16 (L3-hot, reverse order), stages 16KB slabs
//     as plain uint4 copies into dbuf LDS (R7-proven barrier skeleton), MFMA.
// R5/R8 lesson: direct-to-reg frags lose (poor coalescing). R6/R7 lesson:
// barrier scheme irrelevant; K4 bound by moving 512MB f32 with phase gaps.
// This round halves K4's input stream (bf16, L3-resident) instead.

#define B_ 16
#define C_ 32
#define N_ 1024
#define T_ 128
#define R_ 10

typedef __bf16 bf16x8 __attribute__((ext_vector_type(8)));
typedef __bf16 bf16x4 __attribute__((ext_vector_type(4)));
typedef float f32x4 __attribute__((ext_vector_type(4)));

__device__ __forceinline__ void lds_barrier() {
    asm volatile("s_waitcnt lgkmcnt(0)" ::: "memory");
    __builtin_amdgcn_s_barrier();
    asm volatile("" ::: "memory");
}

// ---------------------------------------------------------------- kernel 1 (fast)
// block=(b, 8 n-rows): k = sum_c alpha*x (float4 over t) + x->bf16 store,
// pre-swizzled into [b][c][slab16][row64][256B ^ ((row&7)<<4)] layout.
__global__ __launch_bounds__(256) void k_reduce_cw(const float* __restrict__ x,
                                                   const float* __restrict__ alpha,
                                                   float* __restrict__ k,
                                                   __bf16* __restrict__ xb16) {
    int bid = blockIdx.x;            // B * N/8 = 2048
    int b   = bid >> 7;
    int nc  = bid & 127;
    int tid = threadIdx.x;
    int nl  = tid >> 5;              // 0..7
    int lc  = tid & 31;              // float4 col
    int n   = nc * 8 + nl;
    int slab = nc >> 3;              // n>>6
    int row  = ((nc & 7) << 3) + nl; // n&63 ; row&7 == nl
    int wbyte = (lc * 8) ^ (nl << 4);
    const float4* xb = reinterpret_cast<const float4*>(
        x + ((size_t)(b * C_) * N_ + n) * T_) + lc;
    char* xwb = (char*)xb16 +
        (((size_t)(b * C_) * 16 + slab) * 64 + row) * 256 + wbyte;
    float4 acc = {0.f, 0.f, 0.f, 0.f};
    #pragma unroll 8
    for (int c = 0; c < C_; ++c) {
        float a = alpha[c];
        float4 v = xb[(size_t)c * (N_ * T_ / 4)];
        acc.x += a * v.x; acc.y += a * v.y; acc.z += a * v.z; acc.w += a * v.w;
        bf16x4 hv = {(__bf16)v.x, (__bf16)v.y, (__bf16)v.z, (__bf16)v.w};
        *reinterpret_cast<bf16x4*>(xwb + (size_t)c * (16 * 64 * 256)) = hv;
    }
    reinterpret_cast<float4*>(k + ((size_t)b * N_ + n) * T_)[lc] = acc;
}

// ---------------------------------------------------------------- kernel 1 (fallback)
__global__ __launch_bounds__(256) void k_reduce_c(const float* __restrict__ x,
                                                  const float* __restrict__ alpha,
                                                  float* __restrict__ k) {
    int bid = blockIdx.x;
    int b   = bid >> 7;
    int nc  = bid & 127;
    int tid = threadIdx.x;
    int nl  = tid >> 5;
    int lc  = tid & 31;
    int n   = nc * 8 + nl;
    const float4* xb = reinterpret_cast<const float4*>(
        x + ((size_t)(b * C_) * N_ + n) * T_) + lc;
    float4 acc = {0.f, 0.f, 0.f, 0.f};
    #pragma unroll 8
    for (int c = 0; c < C_; ++c) {
        float a = alpha[c];
        float4 v = xb[(size_t)c * (N_ * T_ / 4)];
        acc.x += a * v.x; acc.y += a * v.y; acc.z += a * v.z; acc.w += a * v.w;
    }
    reinterpret_cast<float4*>(k + ((size_t)b * N_ + n) * T_)[lc] = acc;
}

// ---------------------------------------------------------------- kernel 2
__global__ __launch_bounds__(128) void kw_partial2(const float* __restrict__ k,
                                                   const float* __restrict__ W1,
                                                   const float* __restrict__ W2,
                                                   float* __restrict__ p1,
                                                   float* __restrict__ p2) {
    __shared__ float wl[32][20];
    int bid = blockIdx.x;            // b*32 + ch
    int b   = bid >> 5;
    int ch  = bid & 31;
    int n0  = ch * 32;
    int t   = threadIdx.x;
    for (int i = t; i < 32 * 20; i += 128) {
        int nl = i & 31, q = i >> 5;
        wl[nl][q] = (q < 10) ? W1[q * N_ + n0 + nl] : W2[(q - 10) * N_ + n0 + nl];
    }
    __syncthreads();
    float a1[R_] = {}, a2[R_] = {};
    const float* kb = k + ((size_t)b * N_ + n0) * T_ + t;
    #pragma unroll 2
    for (int g = 0; g < 4; ++g) {
        float kv[8];
        #pragma unroll
        for (int j = 0; j < 8; ++j) kv[j] = kb[(g * 8 + j) * T_];
        #pragma unroll
        for (int j = 0; j < 8; ++j) {
            int nl = g * 8 + j;
            #pragma unroll
            for (int r = 0; r < R_; ++r) {
                a1[r] += kv[j] * wl[nl][r];
                a2[r] += kv[j] * wl[nl][10 + r];
            }
        }
    }
    #pragma unroll
    for (int r = 0; r < R_; ++r) {
        size_t o = (((size_t)b * R_ + r) * 32 + ch) * T_ + t;
        p1[o] = a1[r];
        p2[o] = a2[r];
    }
}

// ---------------------------------------------------------------- kernel 3
// reduce partials directly + scores + softmax -> att[b][t][s] bf16
__global__ __launch_bounds__(128) void scores_softmax3(const float* __restrict__ p1,
                                                       const float* __restrict__ p2,
                                                       __bf16* __restrict__ att) {
    __shared__ __align__(16) float kw1s[T_][12];
    __shared__ __align__(16) float kw2s[T_][12];
    __shared__ float sc[T_][T_ + 1];
    int b = blockIdx.x;
    int t = threadIdx.x;
    #pragma unroll
    for (int r = 0; r < R_; ++r) {
        float s1 = 0.f, s2 = 0.f;
        const float* q1 = p1 + (((size_t)b * R_ + r) * 32) * T_ + t;
        const float* q2 = p2 + (((size_t)b * R_ + r) * 32) * T_ + t;
        #pragma unroll 4
        for (int ch = 0; ch < 32; ++ch) { s1 += q1[ch * T_]; s2 += q2[ch * T_]; }
        kw1s[t][r] = s1; kw2s[t][r] = s2;
    }
    __syncthreads();
    float myw[R_];
    #pragma unroll
    for (int r = 0; r < R_; ++r) myw[r] = kw1s[t][r];
    float mx = -1e30f;
    for (int s = 0; s < T_; ++s) {
        float wv[12];
        const float4* qr = reinterpret_cast<const float4*>(&kw2s[s][0]);
        #pragma unroll
        for (int q = 0; q < 3; ++q) *reinterpret_cast<float4*>(&wv[q * 4]) = qr[q];
        float v = 0.f;
        #pragma unroll
        for (int r = 0; r < R_; ++r) v += myw[r] * wv[r];
        sc[t][s] = v;
        mx = fmaxf(mx, v);
    }
    float sum = 0.f;
    for (int s = 0; s < T_; ++s) {
        float e = __expf(sc[t][s] - mx);
        sc[t][s] = e;
        sum += e;
    }
    float inv = 1.0f / sum;
    __bf16* arow = att + ((size_t)b * T_ + t) * T_;
    for (int s8 = 0; s8 < T_; s8 += 8) {
        bf16x8 hv;
        #pragma unroll
        for (int q = 0; q < 8; ++q) hv[q] = (__bf16)(sc[t][s8 + q] * inv);
        *reinterpret_cast<bf16x8*>(arow + s8) = hv;
    }
}

// ---------------------------------------------------------------- kernel 4 (fast)
// block=(b,c,4 slabs) decoded from REVERSED bid (L3-hot x_bf16 tail first).
// att staged once (32KB swizzled); x_bf16 slabs: plain uint4 copy into dbuf
// (pre-swizzled on disk). R7-proven lds_barrier skeleton, no cvt in loop.
__global__ __launch_bounds__(256, 2) void out_gemm6(const __bf16* __restrict__ xb16,
                                                    const __bf16* __restrict__ att,
                                                    float* __restrict__ out) {
    __shared__ __align__(16) __bf16 attl[T_][T_];      // 32 KB swizzled
    __shared__ __align__(16) __bf16 xsl[2][64][T_];    // 2 x 16 KB (image copies)
    int rbid = (int)gridDim.x - 1 - (int)blockIdx.x;   // reverse for L3 locality
    int sg  = rbid & 3;
    int c   = (rbid >> 2) & 31;
    int b   = rbid >> 7;
    int tid = threadIdx.x;
    char* attb = (char*)&attl[0][0];

    const uint4* ga = reinterpret_cast<const uint4*>(att + (size_t)b * T_ * T_);
    uint4 ar[8];
    #pragma unroll
    for (int i = 0; i < 8; ++i) ar[i] = ga[i * 256 + tid];
    // slab base: each slab = 64*128 bf16 = 1024 uint4
    const uint4* gx0 = reinterpret_cast<const uint4*>(xb16) +
                       ((size_t)((b * C_ + c) * 16 + sg * 4)) * 1024;
    uint4 xr[4];
    #pragma unroll
    for (int q = 0; q < 4; ++q) xr[q] = gx0[q * 256 + tid];
    #pragma unroll
    for (int i = 0; i < 8; ++i) {
        int e = i * 256 + tid, row = e >> 4;
        int bc = ((e & 15) * 16) ^ ((row & 7) << 4);
        *reinterpret_cast<uint4*>(attb + row * 256 + bc) = ar[i];
    }
    {
        uint4* lb = reinterpret_cast<uint4*>(&xsl[0][0][0]);
        #pragma unroll
        for (int q = 0; q < 4; ++q) lb[q * 256 + tid] = xr[q];
    }
    lds_barrier();

    int wave = tid >> 6, lane = tid & 63;
    int r16 = lane & 15, g = lane >> 4;
    int wt = wave & 1, wn = wave >> 1;
    int swz = (r16 & 7) << 4;
    size_t slab0 = ((size_t)(b * C_ + c) * N_ + sg * 256) * T_;

    #pragma unroll
    for (int i = 0; i < 4; ++i) {
        uint4 xn[4];
        if (i < 3) {
            const uint4* gxn = gx0 + (size_t)(i + 1) * 1024;
            #pragma unroll
            for (int q = 0; q < 4; ++q) xn[q] = gxn[q * 256 + tid];
        }
        const char* xbb = (const char*)&xsl[i & 1][0][0];
        f32x4 acc[2][4] = {};
        #pragma unroll
        for (int ks = 0; ks < 4; ++ks) {
            int kc = ks * 64 + g * 16;
            bf16x8 a[4], bx[2];
            #pragma unroll
            for (int tt = 0; tt < 4; ++tt)
                a[tt] = *reinterpret_cast<const bf16x8*>(
                    attb + (wt * 64 + tt * 16 + r16) * 256 + (kc ^ swz));
            #pragma unroll
            for (int nn = 0; nn < 2; ++nn)
                bx[nn] = *reinterpret_cast<const bf16x8*>(
                    xbb + (wn * 32 + nn * 16 + r16) * 256 + (kc ^ swz));
            #pragma unroll
            for (int nn = 0; nn < 2; ++nn)
                #pragma unroll
                for (int tt = 0; tt < 4; ++tt)
                    acc[nn][tt] = __builtin_amdgcn_mfma_f32_16x16x32_bf16(
                        a[tt], bx[nn], acc[nn][tt], 0, 0, 0);
        }
        float* o = out + slab0 + ((size_t)i * 64) * T_;
        #pragma unroll
        for (int nn = 0; nn < 2; ++nn) {
            int n_l = wn * 32 + nn * 16 + r16;
            #pragma unroll
            for (int tt = 0; tt < 4; ++tt)
                *reinterpret_cast<f32x4*>(
                    o + (size_t)n_l * T_ + (wt * 64 + tt * 16 + g * 4)) = acc[nn][tt];
        }
        if (i < 3) {
            uint4* lw = reinterpret_cast<uint4*>(&xsl[(i + 1) & 1][0][0]);
            #pragma unroll
            for (int q = 0; q < 4; ++q) lw[q * 256 + tid] = xn[q];
            lds_barrier();
        }
    }
}

// ---------------------------------------------------------------- kernel 4 (fallback, R7-proven)
__global__ __launch_bounds__(256, 2) void out_gemm4(const float* __restrict__ x,
                                                    const __bf16* __restrict__ att,
                                                    float* __restrict__ out) {
    __shared__ __align__(16) __bf16 attl[T_][T_];
    __shared__ __align__(16) __bf16 xsl[2][64][T_];
    int bid = blockIdx.x;
    int sg  = bid & 3;
    int c   = (bid >> 2) & 31;
    int b   = bid >> 7;
    int tid = threadIdx.x;
    char* attb = (char*)&attl[0][0];
    size_t slab0 = ((size_t)(b * C_ + c) * N_ + (sg * 4) * 64) * T_;

    const uint4* ga = reinterpret_cast<const uint4*>(att + (size_t)b * T_ * T_);
    uint4 ar[8];
    #pragma unroll
    for (int i = 0; i < 8; ++i) ar[i] = ga[i * 256 + tid];
    const float4* gx0 = reinterpret_cast<const float4*>(x + slab0);
    float4 xr[8];
    #pragma unroll
    for (int j = 0; j < 8; ++j) xr[j] = gx0[j * 256 + tid];
    #pragma unroll
    for (int i = 0; i < 8; ++i) {
        int e = i * 256 + tid, row = e >> 4;
        int bc = ((e & 15) * 16) ^ ((row & 7) << 4);
        *reinterpret_cast<uint4*>(attb + row * 256 + bc) = ar[i];
    }
    {
        char* xb0 = (char*)&xsl[0][0][0];
        #pragma unroll
        for (int j = 0; j < 8; ++j) {
            int e = j * 256 + tid, row = e >> 5;
            bf16x4 hv = {(__bf16)xr[j].x, (__bf16)xr[j].y, (__bf16)xr[j].z, (__bf16)xr[j].w};
            *reinterpret_cast<bf16x4*>(xb0 + row * 256 + (((e & 31) * 8) ^ ((row & 7) << 4))) = hv;
        }
    }
    lds_barrier();

    int wave = tid >> 6, lane = tid & 63;
    int r16 = lane & 15, g = lane >> 4;
    int wt = wave & 1, wn = wave >> 1;
    int swz = (r16 & 7) << 4;

    #pragma unroll
    for (int i = 0; i < 4; ++i) {
        float4 xn[8];
        if (i < 3) {
            const float4* gxn = reinterpret_cast<const float4*>(
                x + slab0 + ((size_t)(i + 1) * 64) * T_);
            #pragma unroll
            for (int j = 0; j < 8; ++j) xn[j] = gxn[j * 256 + tid];
        }
        const char* xbb = (const char*)&xsl[i & 1][0][0];
        f32x4 acc[2][4] = {};
        #pragma unroll
        for (int ks = 0; ks < 4; ++ks) {
            int kc = ks * 64 + g * 16;
            bf16x8 a[4], bx[2];
            #pragma unroll
            for (int tt = 0; tt < 4; ++tt)
                a[tt] = *reinterpret_cast<const bf16x8*>(
                    attb + (wt * 64 + tt * 16 + r16) * 256 + (kc ^ swz));
            #pragma unroll
            for (int nn = 0; nn < 2; ++nn)
                bx[nn] = *reinterpret_cast<const bf16x8*>(
                    xbb + (wn * 32 + nn * 16 + r16) * 256 + (kc ^ swz));
            #pragma unroll
            for (int nn = 0; nn < 2; ++nn)
                #pragma unroll
                for (int tt = 0; tt < 4; ++tt)
                    acc[nn][tt] = __builtin_amdgcn_mfma_f32_16x16x32_bf16(
                        a[tt], bx[nn], acc[nn][tt], 0, 0, 0);
        }
        float* o = out + slab0 + ((size_t)i * 64) * T_;
        #pragma unroll
        for (int nn = 0; nn < 2; ++nn) {
            int n_l = wn * 32 + nn * 16 + r16;
            #pragma unroll
            for (int tt = 0; tt < 4; ++tt)
                *reinterpret_cast<f32x4*>(
                    o + (size_t)n_l * T_ + (wt * 64 + tt * 16 + g * 4)) = acc[nn][tt];
        }
        if (i < 3) {
            char* xw = (char*)&xsl[(i + 1) & 1][0][0];
            #pragma unroll
            for (int j = 0; j < 8; ++j) {
                int e = j * 256 + tid, row = e >> 5;
                bf16x4 hv = {(__bf16)xn[j].x, (__bf16)xn[j].y,
                             (__bf16)xn[j].z, (__bf16)xn[j].w};
                *reinterpret_cast<bf16x4*>(
                    xw + row * 256 + (((e & 31) * 8) ^ ((row & 7) << 4))) = hv;
            }
            lds_barrier();
        }
    }
}

// ----------------------------------------------------------------
extern "C" void kernel_launch(void* const* d_in, const int* in_sizes, int n_in,
                              void* d_out, int out_size, void* d_ws, size_t ws_size,
                              hipStream_t stream) {
    const float* x     = (const float*)d_in[0];
    const float* W1    = (const float*)d_in[1];
    const float* W2    = (const float*)d_in[2];
    const float* alpha = (const float*)d_in[3];
    float* out = (float*)d_out;

    const size_t KSZ = (size_t)B_ * N_ * T_;            // 2,097,152 f32
    const size_t PSZ = (size_t)B_ * R_ * 32 * T_;       // 655,360 f32
    const size_t ASZ = (size_t)B_ * T_ * T_;            // bf16 elems
    float* k    = (float*)d_ws;
    float* p1   = k + KSZ;
    float* p2   = p1 + PSZ;
    __bf16* att = (__bf16*)(p2 + PSZ);
    __bf16* xb16 = (__bf16*)((char*)(att + ASZ) + ((16 - (((size_t)(att + ASZ)) & 15)) & 15));
    size_t need = (char*)(xb16 + (size_t)B_ * C_ * N_ * T_) - (char*)d_ws;

    if (ws_size >= need) {
        k_reduce_cw    <<<dim3(B_ * (N_ / 8)), dim3(256), 0, stream>>>(x, alpha, k, xb16);
        kw_partial2    <<<dim3(B_ * 32),       dim3(128), 0, stream>>>(k, W1, W2, p1, p2);
        scores_softmax3<<<dim3(B_),            dim3(128), 0, stream>>>(p1, p2, att);
        out_gemm6      <<<dim3(B_ * C_ * 4),   dim3(256), 0, stream>>>(xb16, att, out);
    } else {
        k_reduce_c     <<<dim3(B_ * (N_ / 8)), dim3(256), 0, stream>>>(x, alpha, k);
        kw_partial2    <<<dim3(B_ * 32),       dim3(128), 0, stream>>>(k, W1, W2, p1, p2);
        scores_softmax3<<<dim3(B_),            dim3(128), 0, stream>>>(p1, p2, att);
        out_gemm4      <<<dim3(B_ * C_ * 4),   dim3(256), 0, stream>>>(x, att, out);
    }
}